// Round 9
// baseline (191.718 us; speedup 1.0000x reference)
//
#include <hip/hip_runtime.h>

// Problem constants
#define S_LEN 2048
#define NH    16
#define DH    64
#define DM    1024
#define NQKV  3072

typedef __attribute__((ext_vector_type(8))) __bf16 bf16x8;
typedef __attribute__((ext_vector_type(4))) float  f32x4;
typedef unsigned short ushort_t;

static __device__ __forceinline__ unsigned short bf16b(float f) {
  return __builtin_bit_cast(unsigned short, (__bf16)f);
}

static __device__ __forceinline__ float exp2v(float x) {
  return __builtin_amdgcn_exp2f(x);   // v_exp_f32: D = 2^S0
}

static __device__ __forceinline__ bf16x8 pack8(float4 f0, float4 f1) {
  uint4 v;
  v.x = ((unsigned)bf16b(f0.y) << 16) | bf16b(f0.x);
  v.y = ((unsigned)bf16b(f0.w) << 16) | bf16b(f0.z);
  v.z = ((unsigned)bf16b(f1.y) << 16) | bf16b(f1.x);
  v.w = ((unsigned)bf16b(f1.w) << 16) | bf16b(f1.z);
  return __builtin_bit_cast(bf16x8, v);
}

static __device__ __forceinline__ void glds16(const void* g, void* l) {
  __builtin_amdgcn_global_load_lds((const __attribute__((address_space(1))) unsigned int*)g,
                                   (__attribute__((address_space(3))) unsigned int*)l, 16, 0, 0);
}

// ---------------- workspace layout (bytes) ----------------
#define OFF_WT  65536ull                          // 3072*1024*2
#define OFF_WOT 6356992ull                        // 1024*1024*2
#define OFF_Q   8454144ull                        // 8 MB
#define OFF_K   16842752ull                       // 8 MB
#define OFF_V   25231360ull                       // 8 MB
#define OFF_AO  33619968ull                       // 8 MB (xb before attn, AO after)

// ---------------- fused prep: fold (MFMA) | transpose | castx ----------------
__global__ __launch_bounds__(256) void k_prep(const float* __restrict__ wqkv,
                                              const float* __restrict__ wout,
                                              const float* __restrict__ x,
                                              const float* __restrict__ logits,
                                              unsigned short* __restrict__ Wt,
                                              unsigned short* __restrict__ Wot,
                                              unsigned short* __restrict__ xb) {
  __shared__ __align__(16) char sbuf[16640];
  int bid = blockIdx.x;
  int t = threadIdx.x;

  if (bid < 256) {
    float* msk = (float*)sbuf;                    // 33 f
    float* Kd  = (float*)(sbuf + 144);            // 64 f
    ushort_t (*Fb)[72] = (ushort_t(*)[72])(sbuf + 416);  // 64x72 bf16
    if (t < 33) msk[t] = 1.0f / (1.0f + __expf(-logits[t]));
    __syncthreads();
    if (t < 64) {
      float acc = msk[0];
      #pragma unroll
      for (int f = 1; f < 32; ++f) {
        int r = (f * t) & 63;
        acc += 2.0f * msk[f] * __cosf((float)r * (6.28318530717958647692f / 64.0f));
      }
      acc += msk[32] * ((t & 1) ? -1.0f : 1.0f);
      Kd[t] = acc * (1.0f / 64.0f);
    }
    __syncthreads();
    for (int idx = t; idx < 4096; idx += 256) {
      int j = idx >> 6, i = idx & 63;
      Fb[j][i] = bf16b(Kd[(j - i) & 63]);
    }
    __syncthreads();

    int lane = t & 63, w = t >> 6;
    int m16 = lane & 15, quad = lane >> 4;
    int kx = bid >> 5, yy = bid & 31;
    int which = yy >> 4, h = yy & 15;
    int base = which * 1024 + h * 64;

    bf16x8 af0 = *(const bf16x8*)(&Fb[w * 16 + m16][quad * 8]);
    bf16x8 af1 = *(const bf16x8*)(&Fb[w * 16 + m16][32 + quad * 8]);

    f32x4 acc[8] = {};
    #pragma unroll 2
    for (int n = 0; n < 8; ++n) {
      const float* Wg = wqkv + (size_t)(kx * 128 + n * 16 + m16) * NQKV + base + quad * 8;
      float4 a0 = *(const float4*)(Wg);
      float4 a1 = *(const float4*)(Wg + 4);
      float4 b0 = *(const float4*)(Wg + 32);
      float4 b1 = *(const float4*)(Wg + 36);
      acc[n] = __builtin_amdgcn_mfma_f32_16x16x32_bf16(af0, pack8(a0, a1), acc[n], 0, 0, 0);
      acc[n] = __builtin_amdgcn_mfma_f32_16x16x32_bf16(af1, pack8(b0, b1), acc[n], 0, 0, 0);
    }
    float sc = (which == 0) ? 0.18033688011112042f : 1.0f;   // 0.125 * log2(e) into q
    #pragma unroll
    for (int n = 0; n < 8; ++n) {
      #pragma unroll
      for (int r = 0; r < 4; ++r) {
        int j = w * 16 + quad * 4 + r;
        Wt[(size_t)(base + j) * DM + kx * 128 + n * 16 + m16] = bf16b(acc[n][r] * sc);
      }
    }
  } else if (bid < 768) {
    float (*Ts)[65] = (float(*)[65])sbuf;
    int b1 = bid - 256;
    if (b1 < 256) {
      int kt = b1 & 15, nt = b1 >> 4;
      int cb = 2048 + nt * 64, kbase = kt * 64;
      #pragma unroll
      for (int p = 0; p < 16; ++p) {
        int kk = p * 4 + (t >> 6);
        Ts[kk][t & 63] = wqkv[(size_t)(kbase + kk) * NQKV + cb + (t & 63)];
      }
      __syncthreads();
      #pragma unroll
      for (int p = 0; p < 16; ++p) {
        int nn = p * 4 + (t >> 6);
        Wt[(size_t)(cb + nn) * DM + kbase + (t & 63)] = bf16b(Ts[t & 63][nn]);
      }
    } else {
      int b2 = b1 - 256;
      int kt = b2 & 15, nt = b2 >> 4;
      int cb = nt * 64, kbase = kt * 64;
      #pragma unroll
      for (int p = 0; p < 16; ++p) {
        int kk = p * 4 + (t >> 6);
        Ts[kk][t & 63] = wout[(size_t)(kbase + kk) * DM + cb + (t & 63)];
      }
      __syncthreads();
      #pragma unroll
      for (int p = 0; p < 16; ++p) {
        int nn = p * 4 + (t >> 6);
        Wot[(size_t)(cb + nn) * DM + kbase + (t & 63)] = bf16b(Ts[t & 63][nn]);
      }
    }
  } else {
    size_t i = ((size_t)(bid - 768) * 256 + t) * 8;
    const float4* xp = (const float4*)(x + i);
    float4 a = xp[0], b = xp[1];
    uint4 v;
    v.x = ((unsigned)bf16b(a.y) << 16) | bf16b(a.x);
    v.y = ((unsigned)bf16b(a.w) << 16) | bf16b(a.z);
    v.z = ((unsigned)bf16b(b.y) << 16) | bf16b(b.x);
    v.w = ((unsigned)bf16b(b.w) << 16) | bf16b(b.z);
    *(uint4*)(xb + i) = v;
  }
}

// ---------------- big-tile GEMM core: 512 threads, 8 waves, 2-slot ring, counted vmcnt ----
template<int BM, int BN, int WCOLS, int MR, int NR>
__device__ __forceinline__ void gemm_core2(const unsigned short* __restrict__ A,
                                           const unsigned short* __restrict__ Bw,
                                           int bm, int bn, unsigned short* smem,
                                           f32x4 (&acc)[MR][NR]) {
  constexpr int SLOT = (BM + BN) * 64;       // shorts per slot
  constexpr int PA = BM / 64, PB = BN / 64;
  constexpr int L = PA + PB;                 // glds16 per thread per slot
  int t = threadIdx.x, lane = t & 63, w = t >> 6;
  int m16 = lane & 15, quad = lane >> 4;
  int wr = (w / WCOLS) * (MR * 16), wc = (w % WCOLS) * (NR * 16);
  int xr = m16 & 7;
  int trow = t >> 3, tcol = t & 7;
  int gsw = (tcol ^ (trow & 7)) * 8;         // pre-swizzled global source, linear LDS dest
  const unsigned short* Ag = A  + (size_t)(bm * BM + trow) * DM + gsw;
  const unsigned short* Bg = Bw + (size_t)(bn * BN + trow) * DM + gsw;
  unsigned short* Al = smem + trow * 64 + tcol * 8;
  unsigned short* Bl = smem + BM * 64 + trow * 64 + tcol * 8;

  // prologue: stage K-steps 0,1 into slots 0,1
  #pragma unroll
  for (int s = 0; s < 2; ++s) {
    #pragma unroll
    for (int p = 0; p < PA; ++p)
      glds16(Ag + (size_t)p * 64 * DM + s * 64, Al + s * SLOT + p * 4096);
    #pragma unroll
    for (int p = 0; p < PB; ++p)
      glds16(Bg + (size_t)p * 64 * DM + s * 64, Bl + s * SLOT + p * 4096);
  }

  #pragma unroll 1
  for (int ks = 0; ks < 16; ++ks) {
    if (ks < 15) asm volatile("s_waitcnt vmcnt(%0)" :: "n"(L) : "memory");
    else         asm volatile("s_waitcnt vmcnt(0)" ::: "memory");
    __builtin_amdgcn_s_barrier();            // my K-step landed everywhere; prev reads done
    __builtin_amdgcn_sched_barrier(0);       // keep ds_reads below the barrier
    const unsigned short* As = smem + (ks & 1) * SLOT;
    const unsigned short* Bs = As + BM * 64;
    #pragma unroll
    for (int kk = 0; kk < 2; ++kk) {
      bf16x8 af[MR], bfr[NR];
      #pragma unroll
      for (int i = 0; i < MR; ++i)
        af[i] = *(const bf16x8*)(As + (wr + i * 16 + m16) * 64 + ((kk * 4 + quad) ^ xr) * 8);
      #pragma unroll
      for (int j = 0; j < NR; ++j)
        bfr[j] = *(const bf16x8*)(Bs + (wc + j * 16 + m16) * 64 + ((kk * 4 + quad) ^ xr) * 8);
      #pragma unroll
      for (int i = 0; i < MR; ++i)
        #pragma unroll
        for (int j = 0; j < NR; ++j)
          acc[i][j] = __builtin_amdgcn_mfma_f32_16x16x32_bf16(af[i], bfr[j], acc[i][j], 0, 0, 0);
    }
    // refill just-freed slot (all waves' ds_reads of it completed before this barrier)
    if (ks < 14) {
      __builtin_amdgcn_s_barrier();
      __builtin_amdgcn_sched_barrier(0);
      int kn = ks + 2;
      #pragma unroll
      for (int p = 0; p < PA; ++p)
        glds16(Ag + (size_t)p * 64 * DM + kn * 64, Al + (ks & 1) * SLOT + p * 4096);
      #pragma unroll
      for (int p = 0; p < PB; ++p)
        glds16(Bg + (size_t)p * 64 * DM + kn * 64, Bl + (ks & 1) * SLOT + p * 4096);
    }
  }
  __syncthreads();   // epilogue reuses smem (Tr buffer)
}

// ---------------- GEMM1: qkv = xb @ Wt^T, 256x192 tiles -> grid (16,16) = 256 blocks = 1/CU ----
__global__ __launch_bounds__(512, 1) void k_gemm_qkv(const unsigned short* __restrict__ xb,
                                                     const unsigned short* __restrict__ Bw,
                                                     unsigned short* __restrict__ Qb,
                                                     unsigned short* __restrict__ Kb,
                                                     unsigned short* __restrict__ Vt) {
  __shared__ __align__(16) unsigned short smem[57344];   // 114688 B (ring; Tr reuses)
  f32x4 acc[8][3] = {};
  int bn = blockIdx.x, bm = blockIdx.y;
  gemm_core2<256, 192, 4, 8, 3>(xb, Bw, bm, bn, smem, acc);

  int t = threadIdx.x, lane = t & 63, w = t >> 6;
  int m16 = lane & 15, quad = lane >> 4;
  int wr = (w >> 2) * 128, wc = (w & 3) * 48;
  int b = bm >> 3, srow = (bm & 7) * 256;
  ushort_t (*Tr)[200] = (ushort_t(*)[200])smem;   // 256 x 200 shorts = 102.4 KB

  #pragma unroll
  for (int i = 0; i < 8; ++i)
    #pragma unroll
    for (int j = 0; j < 3; ++j)
      #pragma unroll
      for (int r = 0; r < 4; ++r)
        Tr[wr + i * 16 + quad * 4 + r][wc + j * 16 + m16] = bf16b(acc[i][j][r]);
  __syncthreads();

  #pragma unroll
  for (int ch = 0; ch < 3; ++ch) {
    int cb = bn * 192 + ch * 64;
    int which = cb >> 10, hcol = (cb >> 6) & 15;
    if (which < 2) {
      int row = t >> 1, part = t & 1;          // 2 x uint4 per thread
      unsigned short* dst = (which ? Kb : Qb) +
          ((size_t)(b * 16 + hcol) * 2048 + srow + row) * 64 + part * 32;
      #pragma unroll
      for (int p = 0; p < 4; ++p)
        *(uint4*)(dst + p * 8) = *(const uint4*)(&Tr[row][ch * 64 + part * 32 + p * 8]);
    } else {
      int d = t & 63, rb = (t >> 6) * 32;      // 32 contiguous rows of one V^T row
      unsigned short* dst = Vt + ((size_t)(b * 16 + hcol) * 64 + d) * 2048 + srow + rb;
      #pragma unroll
      for (int p = 0; p < 4; ++p) {
        unsigned short tmp[8];
        #pragma unroll
        for (int q = 0; q < 8; ++q) tmp[q] = Tr[rb + p * 8 + q][ch * 64 + d];
        *(uint4*)(dst + p * 8) = *(const uint4*)tmp;
      }
    }
  }
}

// ---------------- flash attention: 4 waves x 64 q-rows, 2 blocks/CU, in-register P ----------
// r8: r7's theory (halve LDS reads per MFMA via 64-row wave-tile) kept; r7's BUG fixed.
// global_load_lds writes LDS at wave-uniform base + lane*16 (m104/m108) — the staging
// mapping MUST give every lane an LDS addr of exactly base+lane*16. r7's trow=t>>2 mapping
// violated that (lane 4 computed byte 128, HW wrote byte 64 -> scrambled tiles, absmax 0.198).
// Fix: two virtual 512-thread staging passes, tt = t + i*256, trow=tt>>3, tcol=tt&7 ->
// LDS dest = tt*16 bytes, contiguous per wave-instruction (the proven r6 mapping, done twice).
// Same 4 loads/thread/tile -> all vmcnt counts unchanged.
__global__ __launch_bounds__(256, 2) void k_attn(const unsigned short* __restrict__ Qb,
                                                 const unsigned short* __restrict__ Kb,
                                                 const unsigned short* __restrict__ Vt,
                                                 unsigned short* __restrict__ AO) {
  __shared__ __align__(16) unsigned short smem[32768];   // 65536 B: K[4][64][64] | V[4][64][64]
  int t = threadIdx.x;
  int w = t >> 6, lane = t & 63;
  int m16 = lane & 15, quad = lane >> 4;
  int bid = blockIdx.x;
  int jj = bid >> 3;
  int bh = ((jj & 3) << 3) + (bid & 7);
  int qbase = (jj >> 2) * 256 + w * 64;

  const unsigned short* Qp = Qb + ((size_t)bh * S_LEN + qbase + m16) * DH + quad * 8;
  bf16x8 aq0[4], aq1[4];
  #pragma unroll
  for (int f = 0; f < 4; ++f) {
    aq0[f] = *(const bf16x8*)(Qp + f * 16 * DH);
    aq1[f] = *(const bf16x8*)(Qp + f * 16 * DH + 32);
  }
  const unsigned short* Kbase = Kb + (size_t)bh * S_LEN * DH;
  const unsigned short* Vbase = Vt + (size_t)bh * DH * S_LEN;

  int xr = m16 & 7;
  // sigma key rows: key = c*32 + krow0 + gl*4 (lane-local P for PV A-fragment)
  int krow0 = ((m16 >> 2) << 3) + (m16 & 3);

  // staging: 256 threads x 2 virtual passes (tt = t, t+256); LDS dest = tt*16 bytes —
  // contiguous in lane order per glds16 instruction (HW requirement).
  const unsigned short* KgA[2];
  const unsigned short* VgA[2];
  unsigned short* KlA[2];
  unsigned short* VlA[2];
  #pragma unroll
  for (int i = 0; i < 2; ++i) {
    int tt = t + i * 256;
    int trow = tt >> 3, tcol = tt & 7;
    int fK = (trow & 3) | ((trow >> 1) & 4);   // K chunk swizzle (bit2 from key bit3)
    KgA[i] = Kbase + (size_t)trow * 64 + (tcol ^ fK) * 8;
    VgA[i] = Vbase + (size_t)trow * S_LEN + (tcol ^ (trow & 7)) * 8;
    KlA[i] = smem + tt * 8;
    VlA[i] = smem + 16384 + tt * 8;
  }

  f32x4 o[4][4] = {};
  float l[4] = {0.f, 0.f, 0.f, 0.f};
  f32x4 zero = {0.f, 0.f, 0.f, 0.f};

  // prologue: tiles 0,1,2 into slots 0,1,2 (12 loads/thread in flight)
  #pragma unroll
  for (int tt = 0; tt < 3; ++tt) {
    #pragma unroll
    for (int i = 0; i < 2; ++i) {
      glds16(KgA[i] + (size_t)tt * 4096, KlA[i] + tt * 4096);
      glds16(VgA[i] + tt * 64,           VlA[i] + tt * 4096);
    }
  }

  #pragma unroll 1
  for (int kt = 0; kt < 32; ++kt) {
    // tile kt must have landed; tiles kt+1, kt+2 (4 loads each) stay in flight
    if (kt < 30)      asm volatile("s_waitcnt vmcnt(8)" ::: "memory");
    else if (kt < 31) asm volatile("s_waitcnt vmcnt(4)" ::: "memory");
    else              asm volatile("s_waitcnt vmcnt(0)" ::: "memory");
    __builtin_amdgcn_s_barrier();            // tile kt landed everywhere; tile kt-1 reads done
    __builtin_amdgcn_sched_barrier(0);       // keep ds_reads below the barrier
    // refill tile kt+3 into slot of tile kt-1 (WAR-safe after the barrier)
    if (kt < 29) {
      int ta = kt + 3, sl = ta & 3;
      #pragma unroll
      for (int i = 0; i < 2; ++i) {
        glds16(KgA[i] + (size_t)ta * 4096, KlA[i] + sl * 4096);
        glds16(VgA[i] + ta * 64,           VlA[i] + sl * 4096);
      }
    }
    const unsigned short* Ksh = smem + (kt & 3) * 4096;
    const unsigned short* Vsh = smem + 16384 + (kt & 3) * 4096;

    bf16x8 p[4][2];
    #pragma unroll
    for (int c = 0; c < 2; ++c) {
      f32x4 s[4][2];
      __builtin_amdgcn_s_setprio(1);
      #pragma unroll
      for (int gl = 0; gl < 2; ++gl) {
        int key = c * 32 + krow0 + gl * 4;
        bf16x8 kf0 = *(const bf16x8*)(Ksh + key * 64 + ((quad ^ xr) * 8));
        bf16x8 kf1 = *(const bf16x8*)(Ksh + key * 64 + (((4 + quad) ^ xr) * 8));
        #pragma unroll
        for (int f = 0; f < 4; ++f) {
          s[f][gl] = __builtin_amdgcn_mfma_f32_16x16x32_bf16(kf0, aq0[f], zero, 0, 0, 0);
          s[f][gl] = __builtin_amdgcn_mfma_f32_16x16x32_bf16(kf1, aq1[f], s[f][gl], 0, 0, 0);
        }
      }
      __builtin_amdgcn_s_setprio(0);
      #pragma unroll
      for (int f = 0; f < 4; ++f) {
        float e0 = exp2v(s[f][0][0]), e1 = exp2v(s[f][0][1]);
        float e2 = exp2v(s[f][0][2]), e3 = exp2v(s[f][0][3]);
        float e4 = exp2v(s[f][1][0]), e5 = exp2v(s[f][1][1]);
        float e6 = exp2v(s[f][1][2]), e7 = exp2v(s[f][1][3]);
        l[f] += ((e0 + e1) + (e2 + e3)) + ((e4 + e5) + (e6 + e7));
        uint4 u;
        u.x = ((unsigned)bf16b(e1) << 16) | bf16b(e0);
        u.y = ((unsigned)bf16b(e3) << 16) | bf16b(e2);
        u.z = ((unsigned)bf16b(e5) << 16) | bf16b(e4);
        u.w = ((unsigned)bf16b(e7) << 16) | bf16b(e6);
        p[f][c] = __builtin_bit_cast(bf16x8, u);
      }
    }
    __builtin_amdgcn_s_setprio(1);
    #pragma unroll
    for (int c = 0; c < 2; ++c) {
      #pragma unroll
      for (int j = 0; j < 4; ++j) {
        int dv = j * 16 + m16;
        bf16x8 bv = *(const bf16x8*)(Vsh + dv * 64 + (((c * 4 + quad) ^ xr) * 8));
        #pragma unroll
        for (int f = 0; f < 4; ++f)
          o[f][j] = __builtin_amdgcn_mfma_f32_16x16x32_bf16(p[f][c], bv, o[f][j], 0, 0, 0);
      }
    }
    __builtin_amdgcn_s_setprio(0);
  }

  #pragma unroll
  for (int f = 0; f < 4; ++f) {
    l[f] += __shfl_xor(l[f], 16);
    l[f] += __shfl_xor(l[f], 32);
  }
  int b = bh >> 4, h = bh & 15;
  #pragma unroll
  for (int f = 0; f < 4; ++f) {
    float iv = 1.0f / l[f];
    #pragma unroll
    for (int r = 0; r < 4; ++r) {
      float v0 = __shfl(iv, quad * 4 + r);
      size_t row0 = (size_t)b * S_LEN + qbase + f * 16 + quad * 4 + r;
      unsigned short* d0 = AO + row0 * DM + h * DH + m16;
      #pragma unroll
      for (int j = 0; j < 4; ++j)
        d0[j * 16] = bf16b(o[f][j][r] * v0);
    }
  }
}

// ---------------- GEMM2: out = AO @ Wot^T + bias (fp32 out), 128x128 tiles, grid (8, 32) ----
__global__ __launch_bounds__(512, 1) void k_gemm_out(const unsigned short* __restrict__ A,
                                                     const unsigned short* __restrict__ Bw,
                                                     const float* __restrict__ bias,
                                                     float* __restrict__ out) {
  __shared__ __align__(16) unsigned short smem[32768];   // 65536 B (2 x 32 KB slots)
  f32x4 acc[4][2] = {};
  int bn = blockIdx.x, bm = blockIdx.y;
  gemm_core2<128, 128, 4, 4, 2>(A, Bw, bm, bn, smem, acc);

  int t = threadIdx.x, lane = t & 63, w = t >> 6;
  int m16 = lane & 15, quad = lane >> 4;
  int wr = (w >> 2) * 64, wc = (w & 3) * 32;
  #pragma unroll
  for (int i = 0; i < 4; ++i) {
    int grow = bm * 128 + wr + i * 16 + quad * 4;
    #pragma unroll
    for (int j = 0; j < 2; ++j) {
      int gc = bn * 128 + wc + j * 16 + m16;
      float bb = bias[gc];
      #pragma unroll
      for (int r = 0; r < 4; ++r)
        out[(size_t)(grow + r) * DM + gc] = acc[i][j][r] + bb;
    }
  }
}

extern "C" void kernel_launch(void* const* d_in, const int* in_sizes, int n_in,
                              void* d_out, int out_size, void* d_ws, size_t ws_size,
                              hipStream_t stream) {
  const float* x    = (const float*)d_in[0];
  const float* wqkv = (const float*)d_in[1];
  const float* wout = (const float*)d_in[2];
  const float* bout = (const float*)d_in[3];
  const float* mlog = (const float*)d_in[4];
  char* ws = (char*)d_ws;
  unsigned short* Wt  = (unsigned short*)(ws + OFF_WT);
  unsigned short* Wot = (unsigned short*)(ws + OFF_WOT);
  unsigned short* Qb  = (unsigned short*)(ws + OFF_Q);
  unsigned short* Kb  = (unsigned short*)(ws + OFF_K);
  unsigned short* Vt  = (unsigned short*)(ws + OFF_V);
  unsigned short* xb  = (unsigned short*)(ws + OFF_AO);
  unsigned short* AO  = (unsigned short*)(ws + OFF_AO);
  float* out = (float*)d_out;

  k_prep<<<dim3(2816), dim3(256), 0, stream>>>(wqkv, wout, x, mlog, Wt, Wot, xb);
  k_gemm_qkv<<<dim3(16, 16), dim3(512), 0, stream>>>(xb, Wt, Qb, Kb, Vt);
  k_attn<<<dim3(256), dim3(256), 0, stream>>>(Qb, Kb, Vt, AO);
  k_gemm_out<<<dim3(8, 32), dim3(512), 0, stream>>>(AO, Wot, bout, out);
}

// Round 10
// 188.500 us; speedup vs baseline: 1.0171x; 1.0171x over previous
//
#include <hip/hip_runtime.h>

// Problem constants
#define S_LEN 2048
#define NH    16
#define DH    64
#define DM    1024
#define NQKV  3072

typedef __attribute__((ext_vector_type(8))) __bf16 bf16x8;
typedef __attribute__((ext_vector_type(4))) float  f32x4;
typedef unsigned short ushort_t;

static __device__ __forceinline__ unsigned short bf16b(float f) {
  return __builtin_bit_cast(unsigned short, (__bf16)f);
}

static __device__ __forceinline__ float exp2v(float x) {
  return __builtin_amdgcn_exp2f(x);   // v_exp_f32: D = 2^S0
}

static __device__ __forceinline__ bf16x8 pack8(float4 f0, float4 f1) {
  uint4 v;
  v.x = ((unsigned)bf16b(f0.y) << 16) | bf16b(f0.x);
  v.y = ((unsigned)bf16b(f0.w) << 16) | bf16b(f0.z);
  v.z = ((unsigned)bf16b(f1.y) << 16) | bf16b(f1.x);
  v.w = ((unsigned)bf16b(f1.w) << 16) | bf16b(f1.z);
  return __builtin_bit_cast(bf16x8, v);
}

static __device__ __forceinline__ void glds16(const void* g, void* l) {
  __builtin_amdgcn_global_load_lds((const __attribute__((address_space(1))) unsigned int*)g,
                                   (__attribute__((address_space(3))) unsigned int*)l, 16, 0, 0);
}

// ---------------- workspace layout (bytes) ----------------
#define OFF_WT  65536ull                          // 3072*1024*2
#define OFF_WOT 6356992ull                        // 1024*1024*2
#define OFF_Q   8454144ull                        // 8 MB
#define OFF_K   16842752ull                       // 8 MB
#define OFF_V   25231360ull                       // 8 MB
#define OFF_AO  33619968ull                       // 8 MB (xb before attn, AO after)

// ---------------- fused prep: fold (MFMA) | transpose | castx ----------------
__global__ __launch_bounds__(256) void k_prep(const float* __restrict__ wqkv,
                                              const float* __restrict__ wout,
                                              const float* __restrict__ x,
                                              const float* __restrict__ logits,
                                              unsigned short* __restrict__ Wt,
                                              unsigned short* __restrict__ Wot,
                                              unsigned short* __restrict__ xb) {
  __shared__ __align__(16) char sbuf[16640];
  int bid = blockIdx.x;
  int t = threadIdx.x;

  if (bid < 256) {
    float* msk = (float*)sbuf;                    // 33 f
    float* Kd  = (float*)(sbuf + 144);            // 64 f
    ushort_t (*Fb)[72] = (ushort_t(*)[72])(sbuf + 416);  // 64x72 bf16
    if (t < 33) msk[t] = 1.0f / (1.0f + __expf(-logits[t]));
    __syncthreads();
    if (t < 64) {
      float acc = msk[0];
      #pragma unroll
      for (int f = 1; f < 32; ++f) {
        int r = (f * t) & 63;
        acc += 2.0f * msk[f] * __cosf((float)r * (6.28318530717958647692f / 64.0f));
      }
      acc += msk[32] * ((t & 1) ? -1.0f : 1.0f);
      Kd[t] = acc * (1.0f / 64.0f);
    }
    __syncthreads();
    for (int idx = t; idx < 4096; idx += 256) {
      int j = idx >> 6, i = idx & 63;
      Fb[j][i] = bf16b(Kd[(j - i) & 63]);
    }
    __syncthreads();

    int lane = t & 63, w = t >> 6;
    int m16 = lane & 15, quad = lane >> 4;
    int kx = bid >> 5, yy = bid & 31;
    int which = yy >> 4, h = yy & 15;
    int base = which * 1024 + h * 64;

    bf16x8 af0 = *(const bf16x8*)(&Fb[w * 16 + m16][quad * 8]);
    bf16x8 af1 = *(const bf16x8*)(&Fb[w * 16 + m16][32 + quad * 8]);

    f32x4 acc[8] = {};
    #pragma unroll 2
    for (int n = 0; n < 8; ++n) {
      const float* Wg = wqkv + (size_t)(kx * 128 + n * 16 + m16) * NQKV + base + quad * 8;
      float4 a0 = *(const float4*)(Wg);
      float4 a1 = *(const float4*)(Wg + 4);
      float4 b0 = *(const float4*)(Wg + 32);
      float4 b1 = *(const float4*)(Wg + 36);
      acc[n] = __builtin_amdgcn_mfma_f32_16x16x32_bf16(af0, pack8(a0, a1), acc[n], 0, 0, 0);
      acc[n] = __builtin_amdgcn_mfma_f32_16x16x32_bf16(af1, pack8(b0, b1), acc[n], 0, 0, 0);
    }
    float sc = (which == 0) ? 0.18033688011112042f : 1.0f;   // 0.125 * log2(e) into q
    #pragma unroll
    for (int n = 0; n < 8; ++n) {
      #pragma unroll
      for (int r = 0; r < 4; ++r) {
        int j = w * 16 + quad * 4 + r;
        Wt[(size_t)(base + j) * DM + kx * 128 + n * 16 + m16] = bf16b(acc[n][r] * sc);
      }
    }
  } else if (bid < 768) {
    float (*Ts)[65] = (float(*)[65])sbuf;
    int b1 = bid - 256;
    if (b1 < 256) {
      int kt = b1 & 15, nt = b1 >> 4;
      int cb = 2048 + nt * 64, kbase = kt * 64;
      #pragma unroll
      for (int p = 0; p < 16; ++p) {
        int kk = p * 4 + (t >> 6);
        Ts[kk][t & 63] = wqkv[(size_t)(kbase + kk) * NQKV + cb + (t & 63)];
      }
      __syncthreads();
      #pragma unroll
      for (int p = 0; p < 16; ++p) {
        int nn = p * 4 + (t >> 6);
        Wt[(size_t)(cb + nn) * DM + kbase + (t & 63)] = bf16b(Ts[t & 63][nn]);
      }
    } else {
      int b2 = b1 - 256;
      int kt = b2 & 15, nt = b2 >> 4;
      int cb = nt * 64, kbase = kt * 64;
      #pragma unroll
      for (int p = 0; p < 16; ++p) {
        int kk = p * 4 + (t >> 6);
        Ts[kk][t & 63] = wout[(size_t)(kbase + kk) * DM + cb + (t & 63)];
      }
      __syncthreads();
      #pragma unroll
      for (int p = 0; p < 16; ++p) {
        int nn = p * 4 + (t >> 6);
        Wot[(size_t)(cb + nn) * DM + kbase + (t & 63)] = bf16b(Ts[t & 63][nn]);
      }
    }
  } else {
    size_t i = ((size_t)(bid - 768) * 256 + t) * 8;
    const float4* xp = (const float4*)(x + i);
    float4 a = xp[0], b = xp[1];
    uint4 v;
    v.x = ((unsigned)bf16b(a.y) << 16) | bf16b(a.x);
    v.y = ((unsigned)bf16b(a.w) << 16) | bf16b(a.z);
    v.z = ((unsigned)bf16b(b.y) << 16) | bf16b(b.x);
    v.w = ((unsigned)bf16b(b.w) << 16) | bf16b(b.z);
    *(uint4*)(xb + i) = v;
  }
}

// ---------------- big-tile GEMM core: 512 threads, 8 waves, 2-slot ring, counted vmcnt ----
template<int BM, int BN, int WCOLS, int MR, int NR>
__device__ __forceinline__ void gemm_core2(const unsigned short* __restrict__ A,
                                           const unsigned short* __restrict__ Bw,
                                           int bm, int bn, unsigned short* smem,
                                           f32x4 (&acc)[MR][NR]) {
  constexpr int SLOT = (BM + BN) * 64;       // shorts per slot
  constexpr int PA = BM / 64, PB = BN / 64;
  constexpr int L = PA + PB;                 // glds16 per thread per slot
  int t = threadIdx.x, lane = t & 63, w = t >> 6;
  int m16 = lane & 15, quad = lane >> 4;
  int wr = (w / WCOLS) * (MR * 16), wc = (w % WCOLS) * (NR * 16);
  int xr = m16 & 7;
  int trow = t >> 3, tcol = t & 7;
  int gsw = (tcol ^ (trow & 7)) * 8;         // pre-swizzled global source, linear LDS dest
  const unsigned short* Ag = A  + (size_t)(bm * BM + trow) * DM + gsw;
  const unsigned short* Bg = Bw + (size_t)(bn * BN + trow) * DM + gsw;
  unsigned short* Al = smem + trow * 64 + tcol * 8;
  unsigned short* Bl = smem + BM * 64 + trow * 64 + tcol * 8;

  // prologue: stage K-steps 0,1 into slots 0,1
  #pragma unroll
  for (int s = 0; s < 2; ++s) {
    #pragma unroll
    for (int p = 0; p < PA; ++p)
      glds16(Ag + (size_t)p * 64 * DM + s * 64, Al + s * SLOT + p * 4096);
    #pragma unroll
    for (int p = 0; p < PB; ++p)
      glds16(Bg + (size_t)p * 64 * DM + s * 64, Bl + s * SLOT + p * 4096);
  }

  #pragma unroll 1
  for (int ks = 0; ks < 16; ++ks) {
    if (ks < 15) asm volatile("s_waitcnt vmcnt(%0)" :: "n"(L) : "memory");
    else         asm volatile("s_waitcnt vmcnt(0)" ::: "memory");
    __builtin_amdgcn_s_barrier();            // my K-step landed everywhere; prev reads done
    __builtin_amdgcn_sched_barrier(0);       // keep ds_reads below the barrier
    const unsigned short* As = smem + (ks & 1) * SLOT;
    const unsigned short* Bs = As + BM * 64;
    #pragma unroll
    for (int kk = 0; kk < 2; ++kk) {
      bf16x8 af[MR], bfr[NR];
      #pragma unroll
      for (int i = 0; i < MR; ++i)
        af[i] = *(const bf16x8*)(As + (wr + i * 16 + m16) * 64 + ((kk * 4 + quad) ^ xr) * 8);
      #pragma unroll
      for (int j = 0; j < NR; ++j)
        bfr[j] = *(const bf16x8*)(Bs + (wc + j * 16 + m16) * 64 + ((kk * 4 + quad) ^ xr) * 8);
      #pragma unroll
      for (int i = 0; i < MR; ++i)
        #pragma unroll
        for (int j = 0; j < NR; ++j)
          acc[i][j] = __builtin_amdgcn_mfma_f32_16x16x32_bf16(af[i], bfr[j], acc[i][j], 0, 0, 0);
    }
    // refill just-freed slot (all waves' ds_reads of it completed before this barrier)
    if (ks < 14) {
      __builtin_amdgcn_s_barrier();
      __builtin_amdgcn_sched_barrier(0);
      int kn = ks + 2;
      #pragma unroll
      for (int p = 0; p < PA; ++p)
        glds16(Ag + (size_t)p * 64 * DM + kn * 64, Al + (ks & 1) * SLOT + p * 4096);
      #pragma unroll
      for (int p = 0; p < PB; ++p)
        glds16(Bg + (size_t)p * 64 * DM + kn * 64, Bl + (ks & 1) * SLOT + p * 4096);
    }
  }
  __syncthreads();   // epilogue reuses smem (Tr buffer)
}

// ---------------- GEMM1: qkv = xb @ Wt^T, 256x192 tiles -> grid (16,16) = 256 blocks = 1/CU ----
__global__ __launch_bounds__(512, 1) void k_gemm_qkv(const unsigned short* __restrict__ xb,
                                                     const unsigned short* __restrict__ Bw,
                                                     unsigned short* __restrict__ Qb,
                                                     unsigned short* __restrict__ Kb,
                                                     unsigned short* __restrict__ Vt) {
  __shared__ __align__(16) unsigned short smem[57344];   // 114688 B (ring; Tr reuses)
  f32x4 acc[8][3] = {};
  int bn = blockIdx.x, bm = blockIdx.y;
  gemm_core2<256, 192, 4, 8, 3>(xb, Bw, bm, bn, smem, acc);

  int t = threadIdx.x, lane = t & 63, w = t >> 6;
  int m16 = lane & 15, quad = lane >> 4;
  int wr = (w >> 2) * 128, wc = (w & 3) * 48;
  int b = bm >> 3, srow = (bm & 7) * 256;
  ushort_t (*Tr)[200] = (ushort_t(*)[200])smem;   // 256 x 200 shorts = 102.4 KB

  #pragma unroll
  for (int i = 0; i < 8; ++i)
    #pragma unroll
    for (int j = 0; j < 3; ++j)
      #pragma unroll
      for (int r = 0; r < 4; ++r)
        Tr[wr + i * 16 + quad * 4 + r][wc + j * 16 + m16] = bf16b(acc[i][j][r]);
  __syncthreads();

  #pragma unroll
  for (int ch = 0; ch < 3; ++ch) {
    int cb = bn * 192 + ch * 64;
    int which = cb >> 10, hcol = (cb >> 6) & 15;
    if (which < 2) {
      int row = t >> 1, part = t & 1;          // 2 x uint4 per thread
      unsigned short* dst = (which ? Kb : Qb) +
          ((size_t)(b * 16 + hcol) * 2048 + srow + row) * 64 + part * 32;
      #pragma unroll
      for (int p = 0; p < 4; ++p)
        *(uint4*)(dst + p * 8) = *(const uint4*)(&Tr[row][ch * 64 + part * 32 + p * 8]);
    } else {
      int d = t & 63, rb = (t >> 6) * 32;      // 32 contiguous rows of one V^T row
      unsigned short* dst = Vt + ((size_t)(b * 16 + hcol) * 64 + d) * 2048 + srow + rb;
      #pragma unroll
      for (int p = 0; p < 4; ++p) {
        unsigned short tmp[8];
        #pragma unroll
        for (int q = 0; q < 8; ++q) tmp[q] = Tr[rb + p * 8 + q][ch * 64 + d];
        *(uint4*)(dst + p * 8) = *(const uint4*)tmp;
      }
    }
  }
}

// ---------------- flash attention: 4 waves x 32 q-rows, GRID 512 -> 2 blocks/CU ----------
// r9: r8's regression was occupancy (grid 256 blocks over 256 CUs -> 1 block/CU -> 1 wave/SIMD).
// Fix: split q-range -> 512 blocks x 4 waves x 32 q-rows. 2 co-resident blocks/CU = 8 waves/CU
// (r6 level) but in TWO UNSYNCED barrier groups: group A's softmax VALU overlaps group B's
// QK/PV MFMA, which r6's single 8-wave lockstep group could not do. Keeps r8's verified
// machinery: 4-slot 64 KB ring, single barrier/tile, refill 3-ahead, vmcnt(8), in-register
// sigma-P (conflicts=0), two-virtual-pass staging (LDS dest = tt*16, HW-contiguous).
__global__ __launch_bounds__(256, 2) void k_attn(const unsigned short* __restrict__ Qb,
                                                 const unsigned short* __restrict__ Kb,
                                                 const unsigned short* __restrict__ Vt,
                                                 unsigned short* __restrict__ AO) {
  __shared__ __align__(16) unsigned short smem[32768];   // 65536 B: K[4][64][64] | V[4][64][64]
  int t = threadIdx.x;
  int w = t >> 6, lane = t & 63;
  int m16 = lane & 15, quad = lane >> 4;
  int bid = blockIdx.x;
  int jj = bid >> 3;                 // 0..63
  int bh = ((jj & 3) << 3) + (bid & 7);
  int qbase = (jj >> 2) * 128 + w * 32;   // 16 q-tiles of 128 rows per bh

  const unsigned short* QpA = Qb + ((size_t)bh * S_LEN + qbase + m16) * DH + quad * 8;
  const unsigned short* QpB = QpA + 16 * DH;
  bf16x8 aq0A = *(const bf16x8*)(QpA);
  bf16x8 aq1A = *(const bf16x8*)(QpA + 32);
  bf16x8 aq0B = *(const bf16x8*)(QpB);
  bf16x8 aq1B = *(const bf16x8*)(QpB + 32);
  const unsigned short* Kbase = Kb + (size_t)bh * S_LEN * DH;
  const unsigned short* Vbase = Vt + (size_t)bh * DH * S_LEN;

  int xr = m16 & 7;
  // sigma key rows: key = c*32 + krow0 + gl*4 (lane-local P for PV A-fragment)
  int krow0 = ((m16 >> 2) << 3) + (m16 & 3);

  // staging: 256 threads x 2 virtual passes (tt = t, t+256); LDS dest = tt*16 bytes —
  // contiguous in lane order per glds16 instruction (HW requirement, r8-verified).
  const unsigned short* KgA[2];
  const unsigned short* VgA[2];
  unsigned short* KlA[2];
  unsigned short* VlA[2];
  #pragma unroll
  for (int i = 0; i < 2; ++i) {
    int tt = t + i * 256;
    int trow = tt >> 3, tcol = tt & 7;
    int fK = (trow & 3) | ((trow >> 1) & 4);   // K chunk swizzle (bit2 from key bit3)
    KgA[i] = Kbase + (size_t)trow * 64 + (tcol ^ fK) * 8;
    VgA[i] = Vbase + (size_t)trow * S_LEN + (tcol ^ (trow & 7)) * 8;
    KlA[i] = smem + tt * 8;
    VlA[i] = smem + 16384 + tt * 8;
  }

  f32x4 oA[4] = {}, oB[4] = {};
  float lA = 0.f, lB = 0.f;
  f32x4 zero = {0.f, 0.f, 0.f, 0.f};

  // prologue: tiles 0,1,2 into slots 0,1,2 (12 loads/thread in flight)
  #pragma unroll
  for (int tt = 0; tt < 3; ++tt) {
    #pragma unroll
    for (int i = 0; i < 2; ++i) {
      glds16(KgA[i] + (size_t)tt * 4096, KlA[i] + tt * 4096);
      glds16(VgA[i] + tt * 64,           VlA[i] + tt * 4096);
    }
  }

  #pragma unroll 1
  for (int kt = 0; kt < 32; ++kt) {
    // tile kt must have landed; tiles kt+1, kt+2 (4 loads each) stay in flight
    if (kt < 30)      asm volatile("s_waitcnt vmcnt(8)" ::: "memory");
    else if (kt < 31) asm volatile("s_waitcnt vmcnt(4)" ::: "memory");
    else              asm volatile("s_waitcnt vmcnt(0)" ::: "memory");
    __builtin_amdgcn_s_barrier();            // tile kt landed everywhere; tile kt-1 reads done
    __builtin_amdgcn_sched_barrier(0);       // keep ds_reads below the barrier
    // refill tile kt+3 into slot of tile kt-1 (WAR-safe after the barrier)
    if (kt < 29) {
      int ta = kt + 3, sl = ta & 3;
      #pragma unroll
      for (int i = 0; i < 2; ++i) {
        glds16(KgA[i] + (size_t)ta * 4096, KlA[i] + sl * 4096);
        glds16(VgA[i] + ta * 64,           VlA[i] + sl * 4096);
      }
    }
    const unsigned short* Ksh = smem + (kt & 3) * 4096;
    const unsigned short* Vsh = smem + 16384 + (kt & 3) * 4096;

    bf16x8 pA[2], pB[2];
    #pragma unroll
    for (int c = 0; c < 2; ++c) {
      f32x4 sA[2], sB[2];
      __builtin_amdgcn_s_setprio(1);
      #pragma unroll
      for (int gl = 0; gl < 2; ++gl) {
        int key = c * 32 + krow0 + gl * 4;
        bf16x8 kf0 = *(const bf16x8*)(Ksh + key * 64 + ((quad ^ xr) * 8));
        bf16x8 kf1 = *(const bf16x8*)(Ksh + key * 64 + (((4 + quad) ^ xr) * 8));
        sA[gl] = __builtin_amdgcn_mfma_f32_16x16x32_bf16(kf0, aq0A, zero, 0, 0, 0);
        sA[gl] = __builtin_amdgcn_mfma_f32_16x16x32_bf16(kf1, aq1A, sA[gl], 0, 0, 0);
        sB[gl] = __builtin_amdgcn_mfma_f32_16x16x32_bf16(kf0, aq0B, zero, 0, 0, 0);
        sB[gl] = __builtin_amdgcn_mfma_f32_16x16x32_bf16(kf1, aq1B, sB[gl], 0, 0, 0);
      }
      __builtin_amdgcn_s_setprio(0);
      {
        float e0 = exp2v(sA[0][0]), e1 = exp2v(sA[0][1]);
        float e2 = exp2v(sA[0][2]), e3 = exp2v(sA[0][3]);
        float e4 = exp2v(sA[1][0]), e5 = exp2v(sA[1][1]);
        float e6 = exp2v(sA[1][2]), e7 = exp2v(sA[1][3]);
        lA += ((e0 + e1) + (e2 + e3)) + ((e4 + e5) + (e6 + e7));
        uint4 u;
        u.x = ((unsigned)bf16b(e1) << 16) | bf16b(e0);
        u.y = ((unsigned)bf16b(e3) << 16) | bf16b(e2);
        u.z = ((unsigned)bf16b(e5) << 16) | bf16b(e4);
        u.w = ((unsigned)bf16b(e7) << 16) | bf16b(e6);
        pA[c] = __builtin_bit_cast(bf16x8, u);
        float f0 = exp2v(sB[0][0]), f1 = exp2v(sB[0][1]);
        float f2 = exp2v(sB[0][2]), f3 = exp2v(sB[0][3]);
        float f4 = exp2v(sB[1][0]), f5 = exp2v(sB[1][1]);
        float f6 = exp2v(sB[1][2]), f7 = exp2v(sB[1][3]);
        lB += ((f0 + f1) + (f2 + f3)) + ((f4 + f5) + (f6 + f7));
        uint4 v;
        v.x = ((unsigned)bf16b(f1) << 16) | bf16b(f0);
        v.y = ((unsigned)bf16b(f3) << 16) | bf16b(f2);
        v.z = ((unsigned)bf16b(f5) << 16) | bf16b(f4);
        v.w = ((unsigned)bf16b(f7) << 16) | bf16b(f6);
        pB[c] = __builtin_bit_cast(bf16x8, v);
      }
    }
    __builtin_amdgcn_s_setprio(1);
    #pragma unroll
    for (int c = 0; c < 2; ++c) {
      #pragma unroll
      for (int j = 0; j < 4; ++j) {
        int dv = j * 16 + m16;
        bf16x8 bv = *(const bf16x8*)(Vsh + dv * 64 + (((c * 4 + quad) ^ xr) * 8));
        oA[j] = __builtin_amdgcn_mfma_f32_16x16x32_bf16(pA[c], bv, oA[j], 0, 0, 0);
        oB[j] = __builtin_amdgcn_mfma_f32_16x16x32_bf16(pB[c], bv, oB[j], 0, 0, 0);
      }
    }
    __builtin_amdgcn_s_setprio(0);
  }

  lA += __shfl_xor(lA, 16); lA += __shfl_xor(lA, 32);
  lB += __shfl_xor(lB, 16); lB += __shfl_xor(lB, 32);
  float ivA = 1.0f / lA;
  float ivB = 1.0f / lB;
  int b = bh >> 4, h = bh & 15;
  #pragma unroll
  for (int r = 0; r < 4; ++r) {
    float vA = __shfl(ivA, quad * 4 + r);
    float vB = __shfl(ivB, quad * 4 + r);
    size_t row0 = (size_t)b * S_LEN + qbase + quad * 4 + r;
    unsigned short* d0 = AO + row0 * DM + h * DH + m16;
    unsigned short* d1 = AO + (row0 + 16) * DM + h * DH + m16;
    #pragma unroll
    for (int j = 0; j < 4; ++j) {
      d0[j * 16] = bf16b(oA[j][r] * vA);
      d1[j * 16] = bf16b(oB[j][r] * vB);
    }
  }
}

// ---------------- GEMM2: out = AO @ Wot^T + bias (fp32 out), 128x128 tiles, grid (8, 32) ----
__global__ __launch_bounds__(512, 1) void k_gemm_out(const unsigned short* __restrict__ A,
                                                     const unsigned short* __restrict__ Bw,
                                                     const float* __restrict__ bias,
                                                     float* __restrict__ out) {
  __shared__ __align__(16) unsigned short smem[32768];   // 65536 B (2 x 32 KB slots)
  f32x4 acc[4][2] = {};
  int bn = blockIdx.x, bm = blockIdx.y;
  gemm_core2<128, 128, 4, 4, 2>(A, Bw, bm, bn, smem, acc);

  int t = threadIdx.x, lane = t & 63, w = t >> 6;
  int m16 = lane & 15, quad = lane >> 4;
  int wr = (w >> 2) * 64, wc = (w & 3) * 32;
  #pragma unroll
  for (int i = 0; i < 4; ++i) {
    int grow = bm * 128 + wr + i * 16 + quad * 4;
    #pragma unroll
    for (int j = 0; j < 2; ++j) {
      int gc = bn * 128 + wc + j * 16 + m16;
      float bb = bias[gc];
      #pragma unroll
      for (int r = 0; r < 4; ++r)
        out[(size_t)(grow + r) * DM + gc] = acc[i][j][r] + bb;
    }
  }
}

extern "C" void kernel_launch(void* const* d_in, const int* in_sizes, int n_in,
                              void* d_out, int out_size, void* d_ws, size_t ws_size,
                              hipStream_t stream) {
  const float* x    = (const float*)d_in[0];
  const float* wqkv = (const float*)d_in[1];
  const float* wout = (const float*)d_in[2];
  const float* bout = (const float*)d_in[3];
  const float* mlog = (const float*)d_in[4];
  char* ws = (char*)d_ws;
  unsigned short* Wt  = (unsigned short*)(ws + OFF_WT);
  unsigned short* Wot = (unsigned short*)(ws + OFF_WOT);
  unsigned short* Qb  = (unsigned short*)(ws + OFF_Q);
  unsigned short* Kb  = (unsigned short*)(ws + OFF_K);
  unsigned short* Vt  = (unsigned short*)(ws + OFF_V);
  unsigned short* xb  = (unsigned short*)(ws + OFF_AO);
  unsigned short* AO  = (unsigned short*)(ws + OFF_AO);
  float* out = (float*)d_out;

  k_prep<<<dim3(2816), dim3(256), 0, stream>>>(wqkv, wout, x, mlog, Wt, Wot, xb);
  k_gemm_qkv<<<dim3(16, 16), dim3(512), 0, stream>>>(xb, Wt, Qb, Kb, Vt);
  k_attn<<<dim3(512), dim3(256), 0, stream>>>(Qb, Kb, Vt, AO);
  k_gemm_out<<<dim3(8, 32), dim3(512), 0, stream>>>(AO, Wot, bout, out);
}

// Round 11
// 182.800 us; speedup vs baseline: 1.0488x; 1.0312x over previous
//
#include <hip/hip_runtime.h>

// Problem constants
#define S_LEN 2048
#define NH    16
#define DH    64
#define DM    1024
#define NQKV  3072

typedef __attribute__((ext_vector_type(8))) __bf16 bf16x8;
typedef __attribute__((ext_vector_type(4))) float  f32x4;
typedef unsigned short ushort_t;

static __device__ __forceinline__ unsigned short bf16b(float f) {
  return __builtin_bit_cast(unsigned short, (__bf16)f);
}

static __device__ __forceinline__ float exp2v(float x) {
  return __builtin_amdgcn_exp2f(x);   // v_exp_f32: D = 2^S0
}

static __device__ __forceinline__ bf16x8 pack8(float4 f0, float4 f1) {
  uint4 v;
  v.x = ((unsigned)bf16b(f0.y) << 16) | bf16b(f0.x);
  v.y = ((unsigned)bf16b(f0.w) << 16) | bf16b(f0.z);
  v.z = ((unsigned)bf16b(f1.y) << 16) | bf16b(f1.x);
  v.w = ((unsigned)bf16b(f1.w) << 16) | bf16b(f1.z);
  return __builtin_bit_cast(bf16x8, v);
}

static __device__ __forceinline__ void glds16(const void* g, void* l) {
  __builtin_amdgcn_global_load_lds((const __attribute__((address_space(1))) unsigned int*)g,
                                   (__attribute__((address_space(3))) unsigned int*)l, 16, 0, 0);
}

// ---------------- workspace layout (bytes) ----------------
#define OFF_WT  65536ull                          // 3072*1024*2
#define OFF_WOT 6356992ull                        // 1024*1024*2
#define OFF_Q   8454144ull                        // 8 MB
#define OFF_K   16842752ull                       // 8 MB
#define OFF_V   25231360ull                       // 8 MB
#define OFF_AO  33619968ull                       // 8 MB (xb before attn, AO after)

// ---------------- fused prep: fold (MFMA) | transpose | castx ----------------
__global__ __launch_bounds__(256) void k_prep(const float* __restrict__ wqkv,
                                              const float* __restrict__ wout,
                                              const float* __restrict__ x,
                                              const float* __restrict__ logits,
                                              unsigned short* __restrict__ Wt,
                                              unsigned short* __restrict__ Wot,
                                              unsigned short* __restrict__ xb) {
  __shared__ __align__(16) char sbuf[16640];
  int bid = blockIdx.x;
  int t = threadIdx.x;

  if (bid < 256) {
    float* msk = (float*)sbuf;                    // 33 f
    float* Kd  = (float*)(sbuf + 144);            // 64 f
    ushort_t (*Fb)[72] = (ushort_t(*)[72])(sbuf + 416);  // 64x72 bf16
    if (t < 33) msk[t] = 1.0f / (1.0f + __expf(-logits[t]));
    __syncthreads();
    if (t < 64) {
      float acc = msk[0];
      #pragma unroll
      for (int f = 1; f < 32; ++f) {
        int r = (f * t) & 63;
        acc += 2.0f * msk[f] * __cosf((float)r * (6.28318530717958647692f / 64.0f));
      }
      acc += msk[32] * ((t & 1) ? -1.0f : 1.0f);
      Kd[t] = acc * (1.0f / 64.0f);
    }
    __syncthreads();
    for (int idx = t; idx < 4096; idx += 256) {
      int j = idx >> 6, i = idx & 63;
      Fb[j][i] = bf16b(Kd[(j - i) & 63]);
    }
    __syncthreads();

    int lane = t & 63, w = t >> 6;
    int m16 = lane & 15, quad = lane >> 4;
    int kx = bid >> 5, yy = bid & 31;
    int which = yy >> 4, h = yy & 15;
    int base = which * 1024 + h * 64;

    bf16x8 af0 = *(const bf16x8*)(&Fb[w * 16 + m16][quad * 8]);
    bf16x8 af1 = *(const bf16x8*)(&Fb[w * 16 + m16][32 + quad * 8]);

    f32x4 acc[8] = {};
    #pragma unroll 2
    for (int n = 0; n < 8; ++n) {
      const float* Wg = wqkv + (size_t)(kx * 128 + n * 16 + m16) * NQKV + base + quad * 8;
      float4 a0 = *(const float4*)(Wg);
      float4 a1 = *(const float4*)(Wg + 4);
      float4 b0 = *(const float4*)(Wg + 32);
      float4 b1 = *(const float4*)(Wg + 36);
      acc[n] = __builtin_amdgcn_mfma_f32_16x16x32_bf16(af0, pack8(a0, a1), acc[n], 0, 0, 0);
      acc[n] = __builtin_amdgcn_mfma_f32_16x16x32_bf16(af1, pack8(b0, b1), acc[n], 0, 0, 0);
    }
    float sc = (which == 0) ? 0.18033688011112042f : 1.0f;   // 0.125 * log2(e) into q
    #pragma unroll
    for (int n = 0; n < 8; ++n) {
      #pragma unroll
      for (int r = 0; r < 4; ++r) {
        int j = w * 16 + quad * 4 + r;
        Wt[(size_t)(base + j) * DM + kx * 128 + n * 16 + m16] = bf16b(acc[n][r] * sc);
      }
    }
  } else if (bid < 768) {
    float (*Ts)[65] = (float(*)[65])sbuf;
    int b1 = bid - 256;
    if (b1 < 256) {
      int kt = b1 & 15, nt = b1 >> 4;
      int cb = 2048 + nt * 64, kbase = kt * 64;
      #pragma unroll
      for (int p = 0; p < 16; ++p) {
        int kk = p * 4 + (t >> 6);
        Ts[kk][t & 63] = wqkv[(size_t)(kbase + kk) * NQKV + cb + (t & 63)];
      }
      __syncthreads();
      #pragma unroll
      for (int p = 0; p < 16; ++p) {
        int nn = p * 4 + (t >> 6);
        Wt[(size_t)(cb + nn) * DM + kbase + (t & 63)] = bf16b(Ts[t & 63][nn]);
      }
    } else {
      int b2 = b1 - 256;
      int kt = b2 & 15, nt = b2 >> 4;
      int cb = nt * 64, kbase = kt * 64;
      #pragma unroll
      for (int p = 0; p < 16; ++p) {
        int kk = p * 4 + (t >> 6);
        Ts[kk][t & 63] = wout[(size_t)(kbase + kk) * DM + cb + (t & 63)];
      }
      __syncthreads();
      #pragma unroll
      for (int p = 0; p < 16; ++p) {
        int nn = p * 4 + (t >> 6);
        Wot[(size_t)(cb + nn) * DM + kbase + (t & 63)] = bf16b(Ts[t & 63][nn]);
      }
    }
  } else {
    size_t i = ((size_t)(bid - 768) * 256 + t) * 8;
    const float4* xp = (const float4*)(x + i);
    float4 a = xp[0], b = xp[1];
    uint4 v;
    v.x = ((unsigned)bf16b(a.y) << 16) | bf16b(a.x);
    v.y = ((unsigned)bf16b(a.w) << 16) | bf16b(a.z);
    v.z = ((unsigned)bf16b(b.y) << 16) | bf16b(b.x);
    v.w = ((unsigned)bf16b(b.w) << 16) | bf16b(b.z);
    *(uint4*)(xb + i) = v;
  }
}

// ---------------- big-tile GEMM core: 512 threads, 8 waves, 2-slot ring, counted vmcnt ----
template<int BM, int BN, int WCOLS, int MR, int NR>
__device__ __forceinline__ void gemm_core2(const unsigned short* __restrict__ A,
                                           const unsigned short* __restrict__ Bw,
                                           int bm, int bn, unsigned short* smem,
                                           f32x4 (&acc)[MR][NR]) {
  constexpr int SLOT = (BM + BN) * 64;       // shorts per slot
  constexpr int PA = BM / 64, PB = BN / 64;
  constexpr int L = PA + PB;                 // glds16 per thread per slot
  int t = threadIdx.x, lane = t & 63, w = t >> 6;
  int m16 = lane & 15, quad = lane >> 4;
  int wr = (w / WCOLS) * (MR * 16), wc = (w % WCOLS) * (NR * 16);
  int xr = m16 & 7;
  int trow = t >> 3, tcol = t & 7;
  int gsw = (tcol ^ (trow & 7)) * 8;         // pre-swizzled global source, linear LDS dest
  const unsigned short* Ag = A  + (size_t)(bm * BM + trow) * DM + gsw;
  const unsigned short* Bg = Bw + (size_t)(bn * BN + trow) * DM + gsw;
  unsigned short* Al = smem + trow * 64 + tcol * 8;
  unsigned short* Bl = smem + BM * 64 + trow * 64 + tcol * 8;

  // prologue: stage K-steps 0,1 into slots 0,1
  #pragma unroll
  for (int s = 0; s < 2; ++s) {
    #pragma unroll
    for (int p = 0; p < PA; ++p)
      glds16(Ag + (size_t)p * 64 * DM + s * 64, Al + s * SLOT + p * 4096);
    #pragma unroll
    for (int p = 0; p < PB; ++p)
      glds16(Bg + (size_t)p * 64 * DM + s * 64, Bl + s * SLOT + p * 4096);
  }

  #pragma unroll 1
  for (int ks = 0; ks < 16; ++ks) {
    if (ks < 15) asm volatile("s_waitcnt vmcnt(%0)" :: "n"(L) : "memory");
    else         asm volatile("s_waitcnt vmcnt(0)" ::: "memory");
    __builtin_amdgcn_s_barrier();            // my K-step landed everywhere; prev reads done
    __builtin_amdgcn_sched_barrier(0);       // keep ds_reads below the barrier
    const unsigned short* As = smem + (ks & 1) * SLOT;
    const unsigned short* Bs = As + BM * 64;
    #pragma unroll
    for (int kk = 0; kk < 2; ++kk) {
      bf16x8 af[MR], bfr[NR];
      #pragma unroll
      for (int i = 0; i < MR; ++i)
        af[i] = *(const bf16x8*)(As + (wr + i * 16 + m16) * 64 + ((kk * 4 + quad) ^ xr) * 8);
      #pragma unroll
      for (int j = 0; j < NR; ++j)
        bfr[j] = *(const bf16x8*)(Bs + (wc + j * 16 + m16) * 64 + ((kk * 4 + quad) ^ xr) * 8);
      #pragma unroll
      for (int i = 0; i < MR; ++i)
        #pragma unroll
        for (int j = 0; j < NR; ++j)
          acc[i][j] = __builtin_amdgcn_mfma_f32_16x16x32_bf16(af[i], bfr[j], acc[i][j], 0, 0, 0);
    }
    // refill just-freed slot (all waves' ds_reads of it completed before this barrier)
    if (ks < 14) {
      __builtin_amdgcn_s_barrier();
      __builtin_amdgcn_sched_barrier(0);
      int kn = ks + 2;
      #pragma unroll
      for (int p = 0; p < PA; ++p)
        glds16(Ag + (size_t)p * 64 * DM + kn * 64, Al + (ks & 1) * SLOT + p * 4096);
      #pragma unroll
      for (int p = 0; p < PB; ++p)
        glds16(Bg + (size_t)p * 64 * DM + kn * 64, Bl + (ks & 1) * SLOT + p * 4096);
    }
  }
  __syncthreads();   // epilogue reuses smem (Tr buffer)
}

// ---------------- GEMM1: qkv = xb @ Wt^T, 256x256 tiles, grid 192 (flat, XCD-swizzled) ----
// r10: 256x256/grid-192 measured ~4.7 us faster than 256x192/grid-256 (round6 vs round7 totals
// at fixed prep/out). Added bijective XCD swizzle (T1, nwg%8==0): each XCD gets bm-pairs so its
// A-panels (2 x 512 KB) stay L2-resident; FETCH was 42 MB vs 15 MB ideal.
__global__ __launch_bounds__(512, 1) void k_gemm_qkv(const unsigned short* __restrict__ xb,
                                                     const unsigned short* __restrict__ Bw,
                                                     unsigned short* __restrict__ Qb,
                                                     unsigned short* __restrict__ Kb,
                                                     unsigned short* __restrict__ Vt) {
  __shared__ __align__(16) unsigned short smem[65536];   // 131072 B (ring; Tr reuses)
  f32x4 acc[8][4] = {};
  int bid = blockIdx.x;                 // 0..191
  int xcd = bid & 7, loc = bid >> 3;    // loc 0..23
  int bm = xcd * 2 + (loc / 12);        // XCD x owns bm {2x, 2x+1}
  int bn = loc % 12;
  gemm_core2<256, 256, 4, 8, 4>(xb, Bw, bm, bn, smem, acc);

  int t = threadIdx.x, lane = t & 63, w = t >> 6;
  int m16 = lane & 15, quad = lane >> 4;
  int b = bm >> 3, srow = (bm & 7) * 256;
  int which = bn >> 2;                  // 0=q 1=k 2=v (block-uniform)
  ushort_t (*Tr)[264] = (ushort_t(*)[264])smem;   // 128 x 264 shorts

  if (which < 2) {
    unsigned short* dstB = which ? Kb : Qb;
    int hbase = (bn & 3) * 4;
    #pragma unroll
    for (int ch = 0; ch < 2; ++ch) {
      if ((w >> 2) == ch) {           // waves owning rows ch*128..+127
        #pragma unroll
        for (int i = 0; i < 8; ++i)
          #pragma unroll
          for (int j = 0; j < 4; ++j)
            #pragma unroll
            for (int r = 0; r < 4; ++r)
              Tr[i * 16 + quad * 4 + r][(w & 3) * 64 + j * 16 + m16] = bf16b(acc[i][j][r]);
      }
      __syncthreads();
      int row = t >> 2, qh = t & 3;
      unsigned short* dst = dstB +
          ((size_t)(b * 16 + hbase + qh) * 2048 + srow + ch * 128 + row) * 64;
      #pragma unroll
      for (int p = 0; p < 8; ++p)
        *(uint4*)(dst + p * 8) = *(const uint4*)(&Tr[row][qh * 64 + p * 8]);
      __syncthreads();
    }
  } else {
    int hb = (bn - 8) * 4;
    #pragma unroll
    for (int ch = 0; ch < 2; ++ch) {
      if (((w >> 1) & 1) == ch) {     // waves owning cols ch*128..+127
        #pragma unroll
        for (int i = 0; i < 8; ++i)
          #pragma unroll
          for (int j = 0; j < 4; ++j)
            #pragma unroll
            for (int r = 0; r < 4; ++r)
              Tr[(w & 1) * 64 + j * 16 + m16][(w >> 2) * 128 + i * 16 + quad * 4 + r] =
                  bf16b(acc[i][j][r]);
      }
      __syncthreads();
      int c = t >> 2, qh = t & 3;
      int h = hb + ch * 2 + (c >> 6), d = c & 63;
      unsigned short* dst = Vt + ((size_t)(b * 16 + h) * 64 + d) * 2048 + srow;
      #pragma unroll
      for (int p = 0; p < 8; ++p)
        *(uint4*)(dst + qh * 64 + p * 8) = *(const uint4*)(&Tr[c][qh * 64 + p * 8]);
      __syncthreads();
    }
  }
}

// ---------------- flash attention: 8 waves x 32 q-rows, SINGLE barrier/window, 4-pair ring ----
// Measured best (45.3 us, round 7). One s_barrier per window; refill pair w+3 at window TOP
// into slots of pair w-1 (WAR-safe); steady vmcnt(8); setprio on MFMA clusters; in-register
// sigma-P (conflicts=0). LDS: K ring 8x8KB | V ring 8x8KB = 131072 B, 1 block/CU.
__global__ __launch_bounds__(512, 2) void k_attn(const unsigned short* __restrict__ Qb,
                                                 const unsigned short* __restrict__ Kb,
                                                 const unsigned short* __restrict__ Vt,
                                                 unsigned short* __restrict__ AO) {
  __shared__ __align__(16) unsigned short smem[65536];   // 131072 B
  int t = threadIdx.x;
  int w = t >> 6, lane = t & 63;
  int m16 = lane & 15, quad = lane >> 4;
  int bid = blockIdx.x;
  int jj = bid >> 3;
  int bh = ((jj & 3) << 3) + (bid & 7);
  int qbase = (jj >> 2) * 256 + w * 32;

  const unsigned short* QpA = Qb + ((size_t)bh * S_LEN + qbase + m16) * DH + quad * 8;
  const unsigned short* QpB = QpA + 16 * DH;
  bf16x8 aq0A = *(const bf16x8*)(QpA);
  bf16x8 aq1A = *(const bf16x8*)(QpA + 32);
  bf16x8 aq0B = *(const bf16x8*)(QpB);
  bf16x8 aq1B = *(const bf16x8*)(QpB + 32);
  const unsigned short* Kbase = Kb + (size_t)bh * S_LEN * DH;
  const unsigned short* Vbase = Vt + (size_t)bh * DH * S_LEN;

  int xr = m16 & 7;
  // sigma key rows: key = c*32 + krow0 + gl*4 (lane-local P for PV A-fragment)
  int krow0 = ((m16 >> 2) << 3) + (m16 & 3);

  // staging: 512 threads, 1 K-chunk + 1 V-chunk each per tile.
  int trow = t >> 3;            // 0..63
  int tcol = t & 7;
  int gswzK = tcol ^ ((trow & 3) | ((trow >> 1) & 4));  // f(key) swizzle (bit2 from key bit3)
  int gswzV = tcol ^ (trow & 7);
  const unsigned short* Kg = Kbase + (size_t)trow * 64 + gswzK * 8;
  const unsigned short* Vg = Vbase + (size_t)trow * S_LEN + gswzV * 8;
  unsigned short* Kl = smem + trow * 64 + tcol * 8;              // + slot*4096
  unsigned short* Vl = smem + 32768 + trow * 64 + tcol * 8;      // + slot*4096

  f32x4 oA[4] = {}, oB[4] = {};
  float lA = 0.f, lB = 0.f;
  f32x4 zero = {0.f, 0.f, 0.f, 0.f};

  // prologue: stage tiles 0..5 (pairs 0,1,2) into slots 0..5
  #pragma unroll
  for (int tt = 0; tt < 6; ++tt) {
    glds16(Kg + (size_t)tt * 4096, Kl + tt * 4096);
    glds16(Vg + tt * 64,           Vl + tt * 4096);
  }

#define QK_TILE(KSH, SA, SB)                                                              \
    _Pragma("unroll")                                                                     \
    for (int c = 0; c < 2; ++c) {                                                         \
      _Pragma("unroll")                                                                   \
      for (int gl = 0; gl < 2; ++gl) {                                                    \
        int key = c * 32 + krow0 + gl * 4;                                                \
        bf16x8 kf0 = *(const bf16x8*)((KSH) + key * 64 + ((quad ^ xr) * 8));              \
        bf16x8 kf1 = *(const bf16x8*)((KSH) + key * 64 + (((4 + quad) ^ xr) * 8));        \
        SA[c][gl] = __builtin_amdgcn_mfma_f32_16x16x32_bf16(kf0, aq0A, zero, 0, 0, 0);    \
        SA[c][gl] = __builtin_amdgcn_mfma_f32_16x16x32_bf16(kf1, aq1A, SA[c][gl], 0, 0, 0);\
        SB[c][gl] = __builtin_amdgcn_mfma_f32_16x16x32_bf16(kf0, aq0B, zero, 0, 0, 0);    \
        SB[c][gl] = __builtin_amdgcn_mfma_f32_16x16x32_bf16(kf1, aq1B, SB[c][gl], 0, 0, 0);\
      }                                                                                   \
    }

#define SM_TILE(SA, SB, PA_, PB_)                                                         \
    _Pragma("unroll")                                                                     \
    for (int c = 0; c < 2; ++c) {                                                         \
      float a0 = exp2v(SA[c][0][0]), a1 = exp2v(SA[c][0][1]);                             \
      float a2 = exp2v(SA[c][0][2]), a3 = exp2v(SA[c][0][3]);                             \
      float a4 = exp2v(SA[c][1][0]), a5 = exp2v(SA[c][1][1]);                             \
      float a6 = exp2v(SA[c][1][2]), a7 = exp2v(SA[c][1][3]);                             \
      lA += ((a0 + a1) + (a2 + a3)) + ((a4 + a5) + (a6 + a7));                            \
      uint4 ua;                                                                           \
      ua.x = ((unsigned)bf16b(a1) << 16) | bf16b(a0);                                     \
      ua.y = ((unsigned)bf16b(a3) << 16) | bf16b(a2);                                     \
      ua.z = ((unsigned)bf16b(a5) << 16) | bf16b(a4);                                     \
      ua.w = ((unsigned)bf16b(a7) << 16) | bf16b(a6);                                     \
      PA_[c] = __builtin_bit_cast(bf16x8, ua);                                            \
      float b0 = exp2v(SB[c][0][0]), b1 = exp2v(SB[c][0][1]);                             \
      float b2 = exp2v(SB[c][0][2]), b3 = exp2v(SB[c][0][3]);                             \
      float b4 = exp2v(SB[c][1][0]), b5 = exp2v(SB[c][1][1]);                             \
      float b6 = exp2v(SB[c][1][2]), b7 = exp2v(SB[c][1][3]);                             \
      lB += ((b0 + b1) + (b2 + b3)) + ((b4 + b5) + (b6 + b7));                            \
      uint4 ub;                                                                           \
      ub.x = ((unsigned)bf16b(b1) << 16) | bf16b(b0);                                     \
      ub.y = ((unsigned)bf16b(b3) << 16) | bf16b(b2);                                     \
      ub.z = ((unsigned)bf16b(b5) << 16) | bf16b(b4);                                     \
      ub.w = ((unsigned)bf16b(b7) << 16) | bf16b(b6);                                     \
      PB_[c] = __builtin_bit_cast(bf16x8, ub);                                            \
    }

#define PV_TILE(VSH, PA_, PB_)                                                            \
    _Pragma("unroll")                                                                     \
    for (int c = 0; c < 2; ++c) {                                                         \
      _Pragma("unroll")                                                                   \
      for (int j = 0; j < 4; ++j) {                                                       \
        int dv = j * 16 + m16;                                                            \
        bf16x8 bv = *(const bf16x8*)((VSH) + dv * 64 + (((c * 4 + quad) ^ xr) * 8));      \
        oA[j] = __builtin_amdgcn_mfma_f32_16x16x32_bf16(PA_[c], bv, oA[j], 0, 0, 0);      \
        oB[j] = __builtin_amdgcn_mfma_f32_16x16x32_bf16(PB_[c], bv, oB[j], 0, 0, 0);      \
      }                                                                                   \
    }

  #pragma unroll 1
  for (int wnd = 0; wnd < 16; ++wnd) {
    // pair wnd must have landed; pairs wnd+1, wnd+2 may stay in flight (4 loads each)
    if (wnd < 14)      asm volatile("s_waitcnt vmcnt(8)" ::: "memory");
    else if (wnd < 15) asm volatile("s_waitcnt vmcnt(4)" ::: "memory");
    else               asm volatile("s_waitcnt vmcnt(0)" ::: "memory");
    __builtin_amdgcn_s_barrier();            // pair landed everywhere; pair wnd-1 reads done
    __builtin_amdgcn_sched_barrier(0);       // keep ds_reads below the barrier
    // refill pair wnd+3 into slots of pair wnd-1 (WAR-safe after the barrier)
    if (wnd < 13) {
      int ta = 2 * wnd + 6;
      glds16(Kg + (size_t)ta * 4096,       Kl + (ta & 7) * 4096);
      glds16(Vg + ta * 64,                 Vl + (ta & 7) * 4096);
      glds16(Kg + (size_t)(ta + 1) * 4096, Kl + ((ta + 1) & 7) * 4096);
      glds16(Vg + (ta + 1) * 64,           Vl + ((ta + 1) & 7) * 4096);
    }
    int s0 = (2 * wnd) & 7, s1 = (2 * wnd + 1) & 7;
    const unsigned short* Ka  = smem + s0 * 4096;
    const unsigned short* Kbs = smem + s1 * 4096;
    const unsigned short* Va  = smem + 32768 + s0 * 4096;
    const unsigned short* Vbs = smem + 32768 + s1 * 4096;

    // ---- QK tile a ----
    f32x4 sA[2][2], sB[2][2];
    __builtin_amdgcn_s_setprio(1);
    QK_TILE(Ka, sA, sB)
    __builtin_amdgcn_s_setprio(0);
    // ---- SM tile a -> in-register P fragments ----
    bf16x8 paA[2], paB[2];
    SM_TILE(sA, sB, paA, paB)
    // ---- QK tile b ----
    f32x4 tA[2][2], tB[2][2];
    __builtin_amdgcn_s_setprio(1);
    QK_TILE(Kbs, tA, tB)
    // ---- PV tile a ----
    PV_TILE(Va, paA, paB)
    __builtin_amdgcn_s_setprio(0);
    // ---- SM tile b ----
    bf16x8 pbA[2], pbB[2];
    SM_TILE(tA, tB, pbA, pbB)
    // ---- PV tile b ----
    __builtin_amdgcn_s_setprio(1);
    PV_TILE(Vbs, pbA, pbB)
    __builtin_amdgcn_s_setprio(0);
  }
#undef QK_TILE
#undef SM_TILE
#undef PV_TILE

  lA += __shfl_xor(lA, 16); lA += __shfl_xor(lA, 32);
  lB += __shfl_xor(lB, 16); lB += __shfl_xor(lB, 32);
  float ivA = 1.0f / lA;
  float ivB = 1.0f / lB;
  int b = bh >> 4, h = bh & 15;
  #pragma unroll
  for (int r = 0; r < 4; ++r) {
    float vA = __shfl(ivA, quad * 4 + r);
    float vB = __shfl(ivB, quad * 4 + r);
    size_t row0 = (size_t)b * S_LEN + qbase + quad * 4 + r;
    unsigned short* d0 = AO + row0 * DM + h * DH + m16;
    unsigned short* d1 = AO + (row0 + 16) * DM + h * DH + m16;
    #pragma unroll
    for (int j = 0; j < 4; ++j) {
      d0[j * 16] = bf16b(oA[j][r] * vA);
      d1[j * 16] = bf16b(oB[j][r] * vB);
    }
  }
}

// ---------------- GEMM2: out = AO @ Wot^T + bias (fp32 out), 128x128 tiles, grid (8, 32) ----
__global__ __launch_bounds__(512, 1) void k_gemm_out(const unsigned short* __restrict__ A,
                                                     const unsigned short* __restrict__ Bw,
                                                     const float* __restrict__ bias,
                                                     float* __restrict__ out) {
  __shared__ __align__(16) unsigned short smem[32768];   // 65536 B (2 x 32 KB slots)
  f32x4 acc[4][2] = {};
  int bn = blockIdx.x, bm = blockIdx.y;
  gemm_core2<128, 128, 4, 4, 2>(A, Bw, bm, bn, smem, acc);

  int t = threadIdx.x, lane = t & 63, w = t >> 6;
  int m16 = lane & 15, quad = lane >> 4;
  int wr = (w >> 2) * 64, wc = (w & 3) * 32;
  #pragma unroll
  for (int i = 0; i < 4; ++i) {
    int grow = bm * 128 + wr + i * 16 + quad * 4;
    #pragma unroll
    for (int j = 0; j < 2; ++j) {
      int gc = bn * 128 + wc + j * 16 + m16;
      float bb = bias[gc];
      #pragma unroll
      for (int r = 0; r < 4; ++r)
        out[(size_t)(grow + r) * DM + gc] = acc[i][j][r] + bb;
    }
  }
}

extern "C" void kernel_launch(void* const* d_in, const int* in_sizes, int n_in,
                              void* d_out, int out_size, void* d_ws, size_t ws_size,
                              hipStream_t stream) {
  const float* x    = (const float*)d_in[0];
  const float* wqkv = (const float*)d_in[1];
  const float* wout = (const float*)d_in[2];
  const float* bout = (const float*)d_in[3];
  const float* mlog = (const float*)d_in[4];
  char* ws = (char*)d_ws;
  unsigned short* Wt  = (unsigned short*)(ws + OFF_WT);
  unsigned short* Wot = (unsigned short*)(ws + OFF_WOT);
  unsigned short* Qb  = (unsigned short*)(ws + OFF_Q);
  unsigned short* Kb  = (unsigned short*)(ws + OFF_K);
  unsigned short* Vt  = (unsigned short*)(ws + OFF_V);
  unsigned short* xb  = (unsigned short*)(ws + OFF_AO);
  unsigned short* AO  = (unsigned short*)(ws + OFF_AO);
  float* out = (float*)d_out;

  k_prep<<<dim3(2816), dim3(256), 0, stream>>>(wqkv, wout, x, mlog, Wt, Wot, xb);
  k_gemm_qkv<<<dim3(192), dim3(512), 0, stream>>>(xb, Wt, Qb, Kb, Vt);
  k_attn<<<dim3(256), dim3(512), 0, stream>>>(Qb, Kb, Vt, AO);
  k_gemm_out<<<dim3(8, 32), dim3(512), 0, stream>>>(AO, Wot, bout, out);
}